// Round 1
// baseline (1042.958 us; speedup 1.0000x reference)
//
#include <hip/hip_runtime.h>
#include <hip/hip_bf16.h>
#include <math.h>

namespace {
constexpr int kD = 256;      // embed dim
constexpr int kDOUT = 256;   // out dim
constexpr int kNQ = 65536;   // num query nodes
constexpr int kE = 262144;   // edges
constexpr float kAlpha = 0.2f;
constexpr float kEps = 1e-12f;
}

// c[j] = sum_k a[k][j] * a2[k]   (a is (DOUT, 2D) row-major; j in [0, 512))
__global__ void compute_c_kernel(const float* __restrict__ a,
                                 const float* __restrict__ a2,
                                 float* __restrict__ c) {
  const int j = blockIdx.x * blockDim.x + threadIdx.x;  // 0..511
  float s = 0.f;
#pragma unroll 8
  for (int k = 0; k < kDOUT; ++k) s = fmaf(a[k * (2 * kD) + j], a2[k], s);
  c[j] = s;
}

// One wave (64 lanes) per edge: s = key·c_k + query·c_q; e = exp(-leaky(s));
// atomically accumulate rowsum[q] += e and acc[q,:] += e * key_embed[edge,:]
__global__ __launch_bounds__(256) void edge_pass_kernel(
    const float* __restrict__ key_embed,
    const float* __restrict__ query_embed,
    const int* __restrict__ query_list,
    const float* __restrict__ c,
    float* __restrict__ rowsum,
    float* __restrict__ acc) {
  const int edge = (blockIdx.x << 2) + (threadIdx.x >> 6);
  const int lane = threadIdx.x & 63;

  const float4 k4 = reinterpret_cast<const float4*>(key_embed)[(size_t)edge * (kD / 4) + lane];
  const float4 q4 = reinterpret_cast<const float4*>(query_embed)[(size_t)edge * (kD / 4) + lane];
  const float4 ck = reinterpret_cast<const float4*>(c)[lane];
  const float4 cq = reinterpret_cast<const float4*>(c)[64 + lane];

  float s = k4.x * ck.x + k4.y * ck.y + k4.z * ck.z + k4.w * ck.w
          + q4.x * cq.x + q4.y * cq.y + q4.z * cq.z + q4.w * cq.w;
#pragma unroll
  for (int off = 32; off > 0; off >>= 1) s += __shfl_xor(s, off, 64);

  const float p = (s > 0.f) ? s : kAlpha * s;   // leaky_relu
  const float e = __expf(-p);

  const int q = query_list[edge];
  if (lane == 0) unsafeAtomicAdd(&rowsum[q], e);

  float* dst = acc + (size_t)q * kDOUT + (lane << 2);
  unsafeAtomicAdd(dst + 0, e * k4.x);
  unsafeAtomicAdd(dst + 1, e * k4.y);
  unsafeAtomicAdd(dst + 2, e * k4.z);
  unsafeAtomicAdd(dst + 3, e * k4.w);
}

// C = (A @ trans^T) / rowsum, then elu.  A: (NQ, 256), trans: (DOUT, 256) row-major.
// NT-gemm: C[m][n] = sum_k A[m][k] * trans[n][k].
// 128x128 tile, BK=16, 256 threads (16x16), 8x8 register tile per thread.
__global__ __launch_bounds__(256) void out_gemm_kernel(
    const float* __restrict__ A,
    const float* __restrict__ Bt,       // trans
    const float* __restrict__ rowsum,
    float* __restrict__ out) {
  constexpr int BM = 128, BN = 128, BK = 16;
  __shared__ float As[BK][BM + 4];
  __shared__ float Bs[BK][BN + 4];

  const int tid = threadIdx.x;
  const int tx = tid & 15;   // n direction
  const int ty = tid >> 4;   // m direction
  const int bm = blockIdx.x * BM;
  const int bn = blockIdx.y * BN;

  const int lrow = tid >> 2;          // 0..63
  const int lk4 = (tid & 3) << 2;     // 0,4,8,12

  float accr[8][8] = {};

  for (int kt = 0; kt < kD; kt += BK) {
#pragma unroll
    for (int h = 0; h < 2; ++h) {
      const int row = lrow + h * 64;
      const float4 v = *reinterpret_cast<const float4*>(&A[(size_t)(bm + row) * kD + kt + lk4]);
      As[lk4 + 0][row] = v.x; As[lk4 + 1][row] = v.y;
      As[lk4 + 2][row] = v.z; As[lk4 + 3][row] = v.w;
    }
#pragma unroll
    for (int h = 0; h < 2; ++h) {
      const int nrow = lrow + h * 64;
      const float4 v = *reinterpret_cast<const float4*>(&Bt[(size_t)(bn + nrow) * kD + kt + lk4]);
      Bs[lk4 + 0][nrow] = v.x; Bs[lk4 + 1][nrow] = v.y;
      Bs[lk4 + 2][nrow] = v.z; Bs[lk4 + 3][nrow] = v.w;
    }
    __syncthreads();

#pragma unroll
    for (int k = 0; k < BK; ++k) {
      const float4 a0 = *reinterpret_cast<const float4*>(&As[k][ty * 8]);
      const float4 a1 = *reinterpret_cast<const float4*>(&As[k][ty * 8 + 4]);
      const float4 b0 = *reinterpret_cast<const float4*>(&Bs[k][tx * 8]);
      const float4 b1 = *reinterpret_cast<const float4*>(&Bs[k][tx * 8 + 4]);
      const float am[8] = {a0.x, a0.y, a0.z, a0.w, a1.x, a1.y, a1.z, a1.w};
      const float bv[8] = {b0.x, b0.y, b0.z, b0.w, b1.x, b1.y, b1.z, b1.w};
#pragma unroll
      for (int i = 0; i < 8; ++i)
#pragma unroll
        for (int j = 0; j < 8; ++j) accr[i][j] = fmaf(am[i], bv[j], accr[i][j]);
    }
    __syncthreads();
  }

  // epilogue: divide by rowsum (EPS if zero), elu, store
#pragma unroll
  for (int i = 0; i < 8; ++i) {
    const int row = bm + ty * 8 + i;
    const float rs = rowsum[row];
    const float inv = 1.0f / ((rs == 0.0f) ? kEps : rs);
    float* orow = out + (size_t)row * kDOUT + bn + tx * 8;
#pragma unroll
    for (int j = 0; j < 8; j += 4) {
      float4 v;
      float x;
      x = accr[i][j + 0] * inv; v.x = (x > 0.f) ? x : expm1f(x);
      x = accr[i][j + 1] * inv; v.y = (x > 0.f) ? x : expm1f(x);
      x = accr[i][j + 2] * inv; v.z = (x > 0.f) ? x : expm1f(x);
      x = accr[i][j + 3] * inv; v.w = (x > 0.f) ? x : expm1f(x);
      *reinterpret_cast<float4*>(orow + j) = v;
    }
  }
}

extern "C" void kernel_launch(void* const* d_in, const int* in_sizes, int n_in,
                              void* d_out, int out_size, void* d_ws, size_t ws_size,
                              hipStream_t stream) {
  // inputs: 0 key_list(int,E) [unused], 1 key_embed(f32,E*256), 2 query_list(int,E),
  //         3 query_embed(f32,E*256), 4 a(f32,256*512), 5 a_2(f32,256), 6 trans(f32,256*256)
  const float* key_embed = (const float*)d_in[1];
  const int* query_list = (const int*)d_in[2];
  const float* query_embed = (const float*)d_in[3];
  const float* a = (const float*)d_in[4];
  const float* a2 = (const float*)d_in[5];
  const float* trans = (const float*)d_in[6];
  float* out = (float*)d_out;

  // workspace layout: c[512] | rowsum[NQ] | acc[NQ*256]
  float* ws = (float*)d_ws;
  float* c = ws;
  float* rowsum = ws + 512;
  float* acc = ws + 512 + kNQ;

  hipMemsetAsync(rowsum, 0, ((size_t)kNQ + (size_t)kNQ * kDOUT) * sizeof(float), stream);
  compute_c_kernel<<<2, 256, 0, stream>>>(a, a2, c);
  edge_pass_kernel<<<kE / 4, 256, 0, stream>>>(key_embed, query_embed, query_list, c,
                                               rowsum, acc);
  out_gemm_kernel<<<dim3(kNQ / 128, kDOUT / 128), 256, 0, stream>>>(acc, trans, rowsum, out);
}

// Round 2
// 382.673 us; speedup vs baseline: 2.7255x; 2.7255x over previous
//
#include <hip/hip_runtime.h>
#include <hip/hip_bf16.h>
#include <math.h>

namespace {
constexpr int kD = 256;      // embed dim
constexpr int kDOUT = 256;   // out dim
constexpr int kNQ = 65536;   // num query nodes
constexpr int kE = 262144;   // edges
constexpr float kAlpha = 0.2f;
constexpr float kEps = 1e-12f;
}

// c[j] = sum_k a[k][j] * a2[k]   (a is (DOUT, 2D) row-major; j in [0, 512))
__global__ void compute_c_kernel(const float* __restrict__ a,
                                 const float* __restrict__ a2,
                                 float* __restrict__ c) {
  const int j = blockIdx.x * blockDim.x + threadIdx.x;  // 0..511
  float s = 0.f;
#pragma unroll 8
  for (int k = 0; k < kDOUT; ++k) s = fmaf(a[k * (2 * kD) + j], a2[k], s);
  c[j] = s;
}

// One wave per edge: s = key.c_k + query.c_q; e = exp(-leaky(s)).
// Store e[edge]; histogram count[q]++.
__global__ __launch_bounds__(256) void edge_e_kernel(
    const float* __restrict__ key_embed,
    const float* __restrict__ query_embed,
    const int* __restrict__ query_list,
    const float* __restrict__ c,
    float* __restrict__ e_out,
    int* __restrict__ count) {
  const int edge = (blockIdx.x << 2) + (threadIdx.x >> 6);
  const int lane = threadIdx.x & 63;

  const float4 k4 = reinterpret_cast<const float4*>(key_embed)[(size_t)edge * (kD / 4) + lane];
  const float4 q4 = reinterpret_cast<const float4*>(query_embed)[(size_t)edge * (kD / 4) + lane];
  const float4 ck = reinterpret_cast<const float4*>(c)[lane];
  const float4 cq = reinterpret_cast<const float4*>(c)[64 + lane];

  float s = k4.x * ck.x + k4.y * ck.y + k4.z * ck.z + k4.w * ck.w
          + q4.x * cq.x + q4.y * cq.y + q4.z * cq.z + q4.w * cq.w;
#pragma unroll
  for (int off = 32; off > 0; off >>= 1) s += __shfl_xor(s, off, 64);

  if (lane == 0) {
    const float p = (s > 0.f) ? s : kAlpha * s;   // leaky_relu
    e_out[edge] = __expf(-p);
    atomicAdd(&count[query_list[edge]], 1);
  }
}

// Single-block exclusive scan of count[NQ] -> offsets[NQ+1], plus cursor copy.
__global__ __launch_bounds__(1024) void scan_kernel(const int* __restrict__ count,
                                                    int* __restrict__ offsets,
                                                    int* __restrict__ cursor) {
  __shared__ int partial[1024];
  const int t = threadIdx.x;
  const int base = t * (kNQ / 1024);   // 64 elements each
  int s = 0;
  for (int i = 0; i < kNQ / 1024; ++i) s += count[base + i];
  partial[t] = s;
  __syncthreads();
  // Hillis-Steele inclusive scan over 1024
  for (int off = 1; off < 1024; off <<= 1) {
    int v = (t >= off) ? partial[t - off] : 0;
    __syncthreads();
    partial[t] += v;
    __syncthreads();
  }
  int run = partial[t] - s;   // exclusive prefix for this thread's chunk
  for (int i = 0; i < kNQ / 1024; ++i) {
    offsets[base + i] = run;
    cursor[base + i] = run;
    run += count[base + i];
  }
  if (t == 1023) offsets[kNQ] = run;  // == E
}

// Scatter edge ids into CSR order.
__global__ __launch_bounds__(256) void scatter_kernel(const int* __restrict__ query_list,
                                                      int* __restrict__ cursor,
                                                      int* __restrict__ edge_ids) {
  const int edge = blockIdx.x * 256 + threadIdx.x;
  const int q = query_list[edge];
  const int pos = atomicAdd(&cursor[q], 1);
  edge_ids[pos] = edge;
}

// One wave per query: acc[q,:] = (sum_e e*key_row) / rowsum. Plain stores.
__global__ __launch_bounds__(256) void gather_kernel(
    const float* __restrict__ key_embed,
    const float* __restrict__ e,
    const int* __restrict__ offsets,
    const int* __restrict__ edge_ids,
    float* __restrict__ acc) {
  const int q = (blockIdx.x << 2) + (threadIdx.x >> 6);
  const int lane = threadIdx.x & 63;
  const int s0 = offsets[q], s1 = offsets[q + 1];

  float4 a = {0.f, 0.f, 0.f, 0.f};
  float rs = 0.f;
  for (int i = s0; i < s1; ++i) {
    const int edge = edge_ids[i];
    const float ev = e[edge];
    const float4 k4 = reinterpret_cast<const float4*>(key_embed)[(size_t)edge * (kD / 4) + lane];
    a.x = fmaf(ev, k4.x, a.x);
    a.y = fmaf(ev, k4.y, a.y);
    a.z = fmaf(ev, k4.z, a.z);
    a.w = fmaf(ev, k4.w, a.w);
    rs += ev;
  }
  const float inv = 1.0f / ((rs == 0.f) ? kEps : rs);
  a.x *= inv; a.y *= inv; a.z *= inv; a.w *= inv;
  reinterpret_cast<float4*>(acc)[(size_t)q * (kD / 4) + lane] = a;
}

// out = elu(A @ trans^T).  A: (NQ, 256) pre-normalized, trans: (DOUT, 256) row-major.
// 128x128 tile, BK=16, 256 threads, 8x8 register tile per thread.
__global__ __launch_bounds__(256) void out_gemm_kernel(
    const float* __restrict__ A,
    const float* __restrict__ Bt,       // trans
    float* __restrict__ out) {
  constexpr int BM = 128, BN = 128, BK = 16;
  __shared__ float As[BK][BM + 4];
  __shared__ float Bs[BK][BN + 4];

  const int tid = threadIdx.x;
  const int tx = tid & 15;   // n direction
  const int ty = tid >> 4;   // m direction
  const int bm = blockIdx.x * BM;
  const int bn = blockIdx.y * BN;

  const int lrow = tid >> 2;          // 0..63
  const int lk4 = (tid & 3) << 2;     // 0,4,8,12

  float accr[8][8] = {};

  for (int kt = 0; kt < kD; kt += BK) {
#pragma unroll
    for (int h = 0; h < 2; ++h) {
      const int row = lrow + h * 64;
      const float4 v = *reinterpret_cast<const float4*>(&A[(size_t)(bm + row) * kD + kt + lk4]);
      As[lk4 + 0][row] = v.x; As[lk4 + 1][row] = v.y;
      As[lk4 + 2][row] = v.z; As[lk4 + 3][row] = v.w;
    }
#pragma unroll
    for (int h = 0; h < 2; ++h) {
      const int nrow = lrow + h * 64;
      const float4 v = *reinterpret_cast<const float4*>(&Bt[(size_t)(bn + nrow) * kD + kt + lk4]);
      Bs[lk4 + 0][nrow] = v.x; Bs[lk4 + 1][nrow] = v.y;
      Bs[lk4 + 2][nrow] = v.z; Bs[lk4 + 3][nrow] = v.w;
    }
    __syncthreads();

#pragma unroll
    for (int k = 0; k < BK; ++k) {
      const float4 a0 = *reinterpret_cast<const float4*>(&As[k][ty * 8]);
      const float4 a1 = *reinterpret_cast<const float4*>(&As[k][ty * 8 + 4]);
      const float4 b0 = *reinterpret_cast<const float4*>(&Bs[k][tx * 8]);
      const float4 b1 = *reinterpret_cast<const float4*>(&Bs[k][tx * 8 + 4]);
      const float am[8] = {a0.x, a0.y, a0.z, a0.w, a1.x, a1.y, a1.z, a1.w};
      const float bv[8] = {b0.x, b0.y, b0.z, b0.w, b1.x, b1.y, b1.z, b1.w};
#pragma unroll
      for (int i = 0; i < 8; ++i)
#pragma unroll
        for (int j = 0; j < 8; ++j) accr[i][j] = fmaf(am[i], bv[j], accr[i][j]);
    }
    __syncthreads();
  }

#pragma unroll
  for (int i = 0; i < 8; ++i) {
    const int row = bm + ty * 8 + i;
    float* orow = out + (size_t)row * kDOUT + bn + tx * 8;
#pragma unroll
    for (int j = 0; j < 8; j += 4) {
      float4 v;
      float x;
      x = accr[i][j + 0]; v.x = (x > 0.f) ? x : expm1f(x);
      x = accr[i][j + 1]; v.y = (x > 0.f) ? x : expm1f(x);
      x = accr[i][j + 2]; v.z = (x > 0.f) ? x : expm1f(x);
      x = accr[i][j + 3]; v.w = (x > 0.f) ? x : expm1f(x);
      *reinterpret_cast<float4*>(orow + j) = v;
    }
  }
}

extern "C" void kernel_launch(void* const* d_in, const int* in_sizes, int n_in,
                              void* d_out, int out_size, void* d_ws, size_t ws_size,
                              hipStream_t stream) {
  // inputs: 0 key_list(int,E) [unused], 1 key_embed(f32,E*256), 2 query_list(int,E),
  //         3 query_embed(f32,E*256), 4 a(f32,256*512), 5 a_2(f32,256), 6 trans(f32,256*256)
  const float* key_embed = (const float*)d_in[1];
  const int* query_list = (const int*)d_in[2];
  const float* query_embed = (const float*)d_in[3];
  const float* a = (const float*)d_in[4];
  const float* a2 = (const float*)d_in[5];
  const float* trans = (const float*)d_in[6];
  float* out = (float*)d_out;

  // workspace layout (4B elements):
  // c[512] | e[E] | count[NQ] | offsets[NQ+1] | cursor[NQ] | edge_ids[E] | acc[NQ*256]
  float* ws = (float*)d_ws;
  float* c = ws;
  float* e = ws + 512;
  int* count = (int*)(ws + 512 + kE);
  int* offsets = count + kNQ;
  int* cursor = offsets + kNQ + 1;
  int* edge_ids = cursor + kNQ;
  float* acc = (float*)(edge_ids + kE) + 3;  // keep 16B alignment (offsets had +1)
  // fix alignment: edge_ids+kE is 4B-aligned; acc rows are 16B-accessed via float4.
  // (512 + E + NQ + NQ+1 + NQ + E) % 4 == 1, so +3 makes it a multiple of 4.

  hipMemsetAsync(count, 0, (size_t)kNQ * sizeof(int), stream);
  compute_c_kernel<<<2, 256, 0, stream>>>(a, a2, c);
  edge_e_kernel<<<kE / 4, 256, 0, stream>>>(key_embed, query_embed, query_list, c, e, count);
  scan_kernel<<<1, 1024, 0, stream>>>(count, offsets, cursor);
  scatter_kernel<<<kE / 256, 256, 0, stream>>>(query_list, cursor, edge_ids);
  gather_kernel<<<kNQ / 4, 256, 0, stream>>>(key_embed, e, offsets, edge_ids, acc);
  out_gemm_kernel<<<dim3(kNQ / 128, kDOUT / 128), 256, 0, stream>>>(acc, trans, out);
}

// Round 3
// 310.241 us; speedup vs baseline: 3.3618x; 1.2335x over previous
//
#include <hip/hip_runtime.h>
#include <hip/hip_bf16.h>
#include <math.h>

namespace {
constexpr int kD = 256;      // embed dim
constexpr int kDOUT = 256;   // out dim
constexpr int kNQ = 65536;   // num query nodes
constexpr int kE = 262144;   // edges
constexpr float kAlpha = 0.2f;
constexpr float kEps = 1e-12f;
}

typedef short bf16x8 __attribute__((ext_vector_type(8)));
typedef float f32x4 __attribute__((ext_vector_type(4)));

// c[j] = sum_k a[k][j] * a2[k]   (a is (DOUT, 2D) row-major; j in [0, 512))
__global__ void compute_c_kernel(const float* __restrict__ a,
                                 const float* __restrict__ a2,
                                 float* __restrict__ c) {
  const int j = blockIdx.x * blockDim.x + threadIdx.x;  // 0..511
  float s = 0.f;
#pragma unroll 8
  for (int k = 0; k < kDOUT; ++k) s = fmaf(a[k * (2 * kD) + j], a2[k], s);
  c[j] = s;
}

// zero count[] with a properly-sized grid (replaces pathological 154us rocclr fill)
__global__ void zero_count_kernel(int4* __restrict__ count4) {
  count4[blockIdx.x * 256 + threadIdx.x] = int4{0, 0, 0, 0};
}

// trans (256x256 f32) -> bf16
__global__ void cvt_trans_kernel(const float* __restrict__ t, ushort* __restrict__ tb) {
  const int i = blockIdx.x * 256 + threadIdx.x;  // 0..16383, 4 elems each
  const float4 v = reinterpret_cast<const float4*>(t)[i];
  union { ushort4 u; __hip_bfloat16 h[4]; } p;
  p.h[0] = __float2bfloat16(v.x);
  p.h[1] = __float2bfloat16(v.y);
  p.h[2] = __float2bfloat16(v.z);
  p.h[3] = __float2bfloat16(v.w);
  reinterpret_cast<ushort4*>(tb)[i] = p.u;
}

// One wave per edge: s = key.c_k + query.c_q; e = exp(-leaky(s)).
// Store e[edge]; histogram count[q]++.
__global__ __launch_bounds__(256) void edge_e_kernel(
    const float* __restrict__ key_embed,
    const float* __restrict__ query_embed,
    const int* __restrict__ query_list,
    const float* __restrict__ c,
    float* __restrict__ e_out,
    int* __restrict__ count) {
  const int edge = (blockIdx.x << 2) + (threadIdx.x >> 6);
  const int lane = threadIdx.x & 63;

  const float4 k4 = reinterpret_cast<const float4*>(key_embed)[(size_t)edge * (kD / 4) + lane];
  const float4 q4 = reinterpret_cast<const float4*>(query_embed)[(size_t)edge * (kD / 4) + lane];
  const float4 ck = reinterpret_cast<const float4*>(c)[lane];
  const float4 cq = reinterpret_cast<const float4*>(c)[64 + lane];

  float s = k4.x * ck.x + k4.y * ck.y + k4.z * ck.z + k4.w * ck.w
          + q4.x * cq.x + q4.y * cq.y + q4.z * cq.z + q4.w * cq.w;
#pragma unroll
  for (int off = 32; off > 0; off >>= 1) s += __shfl_xor(s, off, 64);

  if (lane == 0) {
    const float p = (s > 0.f) ? s : kAlpha * s;   // leaky_relu
    e_out[edge] = __expf(-p);
    atomicAdd(&count[query_list[edge]], 1);
  }
}

// Single-block exclusive scan of count[NQ] -> offsets[NQ(+pad)], cursor copy.
__global__ __launch_bounds__(1024) void scan_kernel(const int* __restrict__ count,
                                                    int* __restrict__ offsets,
                                                    int* __restrict__ cursor) {
  __shared__ int partial[1024];
  const int t = threadIdx.x;
  int4 loc[16];
#pragma unroll
  for (int i = 0; i < 16; ++i) loc[i] = reinterpret_cast<const int4*>(count)[t * 16 + i];
  int s = 0;
#pragma unroll
  for (int i = 0; i < 16; ++i) s += loc[i].x + loc[i].y + loc[i].z + loc[i].w;
  partial[t] = s;
  __syncthreads();
  for (int off = 1; off < 1024; off <<= 1) {
    int v = (t >= off) ? partial[t - off] : 0;
    __syncthreads();
    partial[t] += v;
    __syncthreads();
  }
  int run = partial[t] - s;   // exclusive prefix of this thread's chunk
#pragma unroll
  for (int i = 0; i < 16; ++i) {
    const int4 v = loc[i];
    int4 o;
    o.x = run; run += v.x;
    o.y = run; run += v.y;
    o.z = run; run += v.z;
    o.w = run; run += v.w;
    reinterpret_cast<int4*>(offsets)[t * 16 + i] = o;
    reinterpret_cast<int4*>(cursor)[t * 16 + i] = o;
  }
  if (t == 1023) offsets[kNQ] = run;  // == E
}

// Scatter edge ids into CSR order.
__global__ __launch_bounds__(256) void scatter_kernel(const int* __restrict__ query_list,
                                                      int* __restrict__ cursor,
                                                      int* __restrict__ edge_ids) {
  const int edge = blockIdx.x * 256 + threadIdx.x;
  const int q = query_list[edge];
  const int pos = atomicAdd(&cursor[q], 1);
  edge_ids[pos] = edge;
}

// One wave per query: acc[q,:] = (sum_e e*key_row) / rowsum, stored as bf16.
__global__ __launch_bounds__(256) void gather_kernel(
    const float* __restrict__ key_embed,
    const float* __restrict__ e,
    const int* __restrict__ offsets,
    const int* __restrict__ edge_ids,
    ushort* __restrict__ accb) {
  const int q = (blockIdx.x << 2) + (threadIdx.x >> 6);
  const int lane = threadIdx.x & 63;
  const int s0 = offsets[q], s1 = offsets[q + 1];

  float4 a = {0.f, 0.f, 0.f, 0.f};
  float rs = 0.f;
  for (int i = s0; i < s1; ++i) {
    const int edge = edge_ids[i];
    const float ev = e[edge];
    const float4 k4 = reinterpret_cast<const float4*>(key_embed)[(size_t)edge * (kD / 4) + lane];
    a.x = fmaf(ev, k4.x, a.x);
    a.y = fmaf(ev, k4.y, a.y);
    a.z = fmaf(ev, k4.z, a.z);
    a.w = fmaf(ev, k4.w, a.w);
    rs += ev;
  }
  const float inv = 1.0f / ((rs == 0.f) ? kEps : rs);
  union { ushort4 u; __hip_bfloat16 h[4]; } p;
  p.h[0] = __float2bfloat16(a.x * inv);
  p.h[1] = __float2bfloat16(a.y * inv);
  p.h[2] = __float2bfloat16(a.z * inv);
  p.h[3] = __float2bfloat16(a.w * inv);
  reinterpret_cast<ushort4*>(accb + (size_t)q * kD)[lane] = p.u;
}

// out = elu(A @ B^T).  A: (NQ,256) bf16 row-major (pre-normalized), B = trans (256n x 256k) bf16.
// One wave per 16-row strip, full N=256 in registers (16 n-tiles of 16x16x32 MFMA).
// Fragment layouts (verified m89/m91): A/B lane l holds 8 contiguous k at
// k = kt + (l>>4)*8, row/col = l&15.  C/D: col = l&15, row = (l>>4)*4 + reg.
__global__ __launch_bounds__(256) void out_gemm_mfma_kernel(
    const ushort* __restrict__ A,
    const ushort* __restrict__ B,
    float* __restrict__ out) {
  const int wid = threadIdx.x >> 6;
  const int lane = threadIdx.x & 63;
  const int row0 = (blockIdx.x * 4 + wid) * 16;
  const int m = lane & 15;
  const int kb = (lane >> 4) * 8;

  f32x4 acc[16] = {};

  for (int kt = 0; kt < kD; kt += 32) {
    const bf16x8 af = *reinterpret_cast<const bf16x8*>(&A[(size_t)(row0 + m) * kD + kt + kb]);
#pragma unroll
    for (int nt = 0; nt < 16; ++nt) {
      const bf16x8 bf = *reinterpret_cast<const bf16x8*>(&B[(size_t)(nt * 16 + m) * kD + kt + kb]);
      acc[nt] = __builtin_amdgcn_mfma_f32_16x16x32_bf16(af, bf, acc[nt], 0, 0, 0);
    }
  }

#pragma unroll
  for (int nt = 0; nt < 16; ++nt) {
#pragma unroll
    for (int r = 0; r < 4; ++r) {
      const int row = row0 + (lane >> 4) * 4 + r;
      const int col = nt * 16 + (lane & 15);
      const float x = acc[nt][r];
      out[(size_t)row * kDOUT + col] = (x > 0.f) ? x : expm1f(x);
    }
  }
}

extern "C" void kernel_launch(void* const* d_in, const int* in_sizes, int n_in,
                              void* d_out, int out_size, void* d_ws, size_t ws_size,
                              hipStream_t stream) {
  // inputs: 0 key_list(int,E) [unused], 1 key_embed(f32,E*256), 2 query_list(int,E),
  //         3 query_embed(f32,E*256), 4 a(f32,256*512), 5 a_2(f32,256), 6 trans(f32,256*256)
  const float* key_embed = (const float*)d_in[1];
  const int* query_list = (const int*)d_in[2];
  const float* query_embed = (const float*)d_in[3];
  const float* a = (const float*)d_in[4];
  const float* a2 = (const float*)d_in[5];
  const float* trans = (const float*)d_in[6];
  float* out = (float*)d_out;

  // workspace layout (float units, all 16B-aligned):
  // c[512] | e[E] | count[NQ] | offsets[NQ+4] | cursor[NQ] | edge_ids[E] | pad3
  // | acc_bf16[NQ*256 ushort] | trans_bf16[256*256 ushort]
  float* ws = (float*)d_ws;
  float* c = ws;
  float* e = ws + 512;
  int* count = (int*)(ws + 512 + kE);
  int* offsets = count + kNQ;
  int* cursor = offsets + kNQ + 4;
  int* edge_ids = cursor + kNQ;
  float* base2 = (float*)(edge_ids + kE) + 3;          // -> multiple of 4 floats
  ushort* accb = (ushort*)base2;                        // NQ*256 bf16
  ushort* transb = (ushort*)(base2 + kNQ * (kD / 2));   // 256*256 bf16

  zero_count_kernel<<<kNQ / 4 / 256, 256, 0, stream>>>((int4*)count);
  compute_c_kernel<<<2, 256, 0, stream>>>(a, a2, c);
  cvt_trans_kernel<<<kDOUT * kD / 4 / 256, 256, 0, stream>>>(trans, transb);
  edge_e_kernel<<<kE / 4, 256, 0, stream>>>(key_embed, query_embed, query_list, c, e, count);
  scan_kernel<<<1, 1024, 0, stream>>>(count, offsets, cursor);
  scatter_kernel<<<kE / 256, 256, 0, stream>>>(query_list, cursor, edge_ids);
  gather_kernel<<<kNQ / 4, 256, 0, stream>>>(key_embed, e, offsets, edge_ids, accb);
  out_gemm_mfma_kernel<<<kNQ / 64, 256, 0, stream>>>(accb, transb, out);
}

// Round 4
// 281.425 us; speedup vs baseline: 3.7060x; 1.1024x over previous
//
#include <hip/hip_runtime.h>
#include <hip/hip_bf16.h>
#include <math.h>

namespace {
constexpr int kD = 256;      // embed dim
constexpr int kDOUT = 256;   // out dim
constexpr int kNQ = 65536;   // num query nodes
constexpr int kE = 262144;   // edges
constexpr float kAlpha = 0.2f;
constexpr float kEps = 1e-12f;
}

typedef short bf16x8 __attribute__((ext_vector_type(8)));
typedef float f32x4 __attribute__((ext_vector_type(4)));

// c[j] = sum_k a[k][j] * a2[k]   (a is (DOUT, 2D) row-major; j in [0, 512))
__global__ void compute_c_kernel(const float* __restrict__ a,
                                 const float* __restrict__ a2,
                                 float* __restrict__ c) {
  const int j = blockIdx.x * blockDim.x + threadIdx.x;  // 0..511
  float s = 0.f;
#pragma unroll 8
  for (int k = 0; k < kDOUT; ++k) s = fmaf(a[k * (2 * kD) + j], a2[k], s);
  c[j] = s;
}

// zero count[] with a properly-sized grid
__global__ void zero_count_kernel(int4* __restrict__ count4) {
  count4[blockIdx.x * 256 + threadIdx.x] = int4{0, 0, 0, 0};
}

// trans (256x256 f32) -> bf16
__global__ void cvt_trans_kernel(const float* __restrict__ t, ushort* __restrict__ tb) {
  const int i = blockIdx.x * 256 + threadIdx.x;  // 4 elems each
  const float4 v = reinterpret_cast<const float4*>(t)[i];
  union { ushort4 u; __hip_bfloat16 h[4]; } p;
  p.h[0] = __float2bfloat16(v.x);
  p.h[1] = __float2bfloat16(v.y);
  p.h[2] = __float2bfloat16(v.z);
  p.h[3] = __float2bfloat16(v.w);
  reinterpret_cast<ushort4*>(tb)[i] = p.u;
}

// histogram of query_list into count[]
__global__ __launch_bounds__(256) void hist_kernel(const int* __restrict__ query_list,
                                                   int* __restrict__ count) {
  const int i = blockIdx.x * 256 + threadIdx.x;
  const int4 q = reinterpret_cast<const int4*>(query_list)[i];
  atomicAdd(&count[q.x], 1);
  atomicAdd(&count[q.y], 1);
  atomicAdd(&count[q.z], 1);
  atomicAdd(&count[q.w], 1);
}

// Single-block exclusive scan of count[NQ] -> offsets, cursor copy.
__global__ __launch_bounds__(1024) void scan_kernel(const int* __restrict__ count,
                                                    int* __restrict__ offsets,
                                                    int* __restrict__ cursor) {
  __shared__ int partial[1024];
  const int t = threadIdx.x;
  int4 loc[16];
#pragma unroll
  for (int i = 0; i < 16; ++i) loc[i] = reinterpret_cast<const int4*>(count)[t * 16 + i];
  int s = 0;
#pragma unroll
  for (int i = 0; i < 16; ++i) s += loc[i].x + loc[i].y + loc[i].z + loc[i].w;
  partial[t] = s;
  __syncthreads();
  for (int off = 1; off < 1024; off <<= 1) {
    int v = (t >= off) ? partial[t - off] : 0;
    __syncthreads();
    partial[t] += v;
    __syncthreads();
  }
  int run = partial[t] - s;
#pragma unroll
  for (int i = 0; i < 16; ++i) {
    const int4 v = loc[i];
    int4 o;
    o.x = run; run += v.x;
    o.y = run; run += v.y;
    o.z = run; run += v.z;
    o.w = run; run += v.w;
    reinterpret_cast<int4*>(offsets)[t * 16 + i] = o;
    reinterpret_cast<int4*>(cursor)[t * 16 + i] = o;
  }
  if (t == 1023) offsets[kNQ] = run;  // == E
}

// Scatter edge ids into CSR order.
__global__ __launch_bounds__(256) void scatter_kernel(const int* __restrict__ query_list,
                                                      int* __restrict__ cursor,
                                                      int* __restrict__ edge_ids) {
  const int edge = blockIdx.x * 256 + threadIdx.x;
  const int q = query_list[edge];
  const int pos = atomicAdd(&cursor[q], 1);
  edge_ids[pos] = edge;
}

// One wave per query. For each CSR edge: read key/query rows, compute
// s = key.c_k + query.c_q, e = exp(-leaky(s)), accumulate e*key_row and rowsum.
// Normalize and store bf16 acc row. Replaces the old edge_e + gather passes.
__global__ __launch_bounds__(256) void fused_gather_kernel(
    const float* __restrict__ key_embed,
    const float* __restrict__ query_embed,
    const float* __restrict__ c,
    const int* __restrict__ offsets,
    const int* __restrict__ edge_ids,
    ushort* __restrict__ accb) {
  const int q = (blockIdx.x << 2) + (threadIdx.x >> 6);
  const int lane = threadIdx.x & 63;
  const int s0 = offsets[q], s1 = offsets[q + 1];

  const float4 ck = reinterpret_cast<const float4*>(c)[lane];
  const float4 cq = reinterpret_cast<const float4*>(c)[64 + lane];

  float4 a = {0.f, 0.f, 0.f, 0.f};
  float rs = 0.f;

  for (int base = s0; base < s1; base += 64) {
    const int cnt = min(64, s1 - base);
    const int myid = (base + lane < s1) ? edge_ids[base + lane] : 0;
    for (int i = 0; i < cnt; ++i) {
      const int edge = __shfl(myid, i, 64);
      const float4 k4 = reinterpret_cast<const float4*>(key_embed)[(size_t)edge * (kD / 4) + lane];
      const float4 q4 = reinterpret_cast<const float4*>(query_embed)[(size_t)edge * (kD / 4) + lane];
      float s = k4.x * ck.x + k4.y * ck.y + k4.z * ck.z + k4.w * ck.w
              + q4.x * cq.x + q4.y * cq.y + q4.z * cq.z + q4.w * cq.w;
#pragma unroll
      for (int off = 32; off > 0; off >>= 1) s += __shfl_xor(s, off, 64);
      const float p = (s > 0.f) ? s : kAlpha * s;   // leaky_relu
      const float ev = __expf(-p);
      a.x = fmaf(ev, k4.x, a.x);
      a.y = fmaf(ev, k4.y, a.y);
      a.z = fmaf(ev, k4.z, a.z);
      a.w = fmaf(ev, k4.w, a.w);
      rs += ev;
    }
  }

  const float inv = 1.0f / ((rs == 0.f) ? kEps : rs);
  union { ushort4 u; __hip_bfloat16 h[4]; } p;
  p.h[0] = __float2bfloat16(a.x * inv);
  p.h[1] = __float2bfloat16(a.y * inv);
  p.h[2] = __float2bfloat16(a.z * inv);
  p.h[3] = __float2bfloat16(a.w * inv);
  reinterpret_cast<ushort4*>(accb + (size_t)q * kD)[lane] = p.u;
}

// out = elu(A @ B^T).  A: (NQ,256) bf16 row-major (pre-normalized), B = trans bf16.
// One wave per 16-row strip, full N=256 in registers (16 n-tiles of 16x16x32 MFMA).
__global__ __launch_bounds__(256) void out_gemm_mfma_kernel(
    const ushort* __restrict__ A,
    const ushort* __restrict__ B,
    float* __restrict__ out) {
  const int wid = threadIdx.x >> 6;
  const int lane = threadIdx.x & 63;
  const int row0 = (blockIdx.x * 4 + wid) * 16;
  const int m = lane & 15;
  const int kb = (lane >> 4) * 8;

  f32x4 acc[16] = {};

  for (int kt = 0; kt < kD; kt += 32) {
    const bf16x8 af = *reinterpret_cast<const bf16x8*>(&A[(size_t)(row0 + m) * kD + kt + kb]);
#pragma unroll
    for (int nt = 0; nt < 16; ++nt) {
      const bf16x8 bf = *reinterpret_cast<const bf16x8*>(&B[(size_t)(nt * 16 + m) * kD + kt + kb]);
      acc[nt] = __builtin_amdgcn_mfma_f32_16x16x32_bf16(af, bf, acc[nt], 0, 0, 0);
    }
  }

#pragma unroll
  for (int nt = 0; nt < 16; ++nt) {
#pragma unroll
    for (int r = 0; r < 4; ++r) {
      const int row = row0 + (lane >> 4) * 4 + r;
      const int col = nt * 16 + (lane & 15);
      const float x = acc[nt][r];
      out[(size_t)row * kDOUT + col] = (x > 0.f) ? x : expm1f(x);
    }
  }
}

extern "C" void kernel_launch(void* const* d_in, const int* in_sizes, int n_in,
                              void* d_out, int out_size, void* d_ws, size_t ws_size,
                              hipStream_t stream) {
  // inputs: 0 key_list(int,E) [unused], 1 key_embed(f32,E*256), 2 query_list(int,E),
  //         3 query_embed(f32,E*256), 4 a(f32,256*512), 5 a_2(f32,256), 6 trans(f32,256*256)
  const float* key_embed = (const float*)d_in[1];
  const int* query_list = (const int*)d_in[2];
  const float* query_embed = (const float*)d_in[3];
  const float* a = (const float*)d_in[4];
  const float* a2 = (const float*)d_in[5];
  const float* trans = (const float*)d_in[6];
  float* out = (float*)d_out;

  // workspace layout (float units, all 16B-aligned):
  // c[512] | count[NQ] | offsets[NQ+4] | cursor[NQ] | edge_ids[E] | pad
  // | acc_bf16[NQ*256 ushort] | trans_bf16[256*256 ushort]
  float* ws = (float*)d_ws;
  float* c = ws;
  int* count = (int*)(ws + 512);
  int* offsets = count + kNQ;
  int* cursor = offsets + kNQ + 4;
  int* edge_ids = cursor + kNQ;
  float* base2 = (float*)(edge_ids + kE);              // 512+NQ+NQ+4+NQ+E ints: mult of 4
  ushort* accb = (ushort*)base2;                        // NQ*256 bf16
  ushort* transb = (ushort*)(base2 + kNQ * (kD / 2));   // 256*256 bf16

  zero_count_kernel<<<kNQ / 4 / 256, 256, 0, stream>>>((int4*)count);
  compute_c_kernel<<<2, 256, 0, stream>>>(a, a2, c);
  cvt_trans_kernel<<<kDOUT * kD / 4 / 256, 256, 0, stream>>>(trans, transb);
  hist_kernel<<<kE / 4 / 256, 256, 0, stream>>>(query_list, count);
  scan_kernel<<<1, 1024, 0, stream>>>(count, offsets, cursor);
  scatter_kernel<<<kE / 256, 256, 0, stream>>>(query_list, cursor, edge_ids);
  fused_gather_kernel<<<kNQ / 4, 256, 0, stream>>>(key_embed, query_embed, c, offsets,
                                                   edge_ids, accb);
  out_gemm_mfma_kernel<<<kNQ / 64, 256, 0, stream>>>(accb, transb, out);
}